// Round 5
// baseline (4303.236 us; speedup 1.0000x reference)
//
#include <hip/hip_runtime.h>
#include <hip/hip_bf16.h>

typedef __attribute__((ext_vector_type(8))) __bf16 bf16x8;
typedef __attribute__((ext_vector_type(4))) __bf16 bf16x4;
typedef __attribute__((ext_vector_type(4))) float f32x4;

#define NBATCH 64
#define NSEQ   512
#define DMODEL 1024
#define NHEAD  16
#define DHEAD  64
#define MROWS  (NBATCH * NSEQ)   // 32768

static __device__ __forceinline__ void gload_lds16(const void* gp, void* lp) {
  __builtin_amdgcn_global_load_lds(
      (__attribute__((address_space(1))) const void*)gp,
      (__attribute__((address_space(3))) void*)lp,
      16, 0, 0);
}

// ---------------------------------------------------------------- merged convert
__global__ void cvt_all_kernel(const float* __restrict__ x, const float* __restrict__ Wq,
                               const float* __restrict__ Wk, const float* __restrict__ Wv,
                               const float* __restrict__ Wo,
                               __bf16* __restrict__ xb, __bf16* __restrict__ Wqkvb,
                               __bf16* __restrict__ Wob) {
  constexpr int NX = (MROWS * DMODEL) / 4;          // 8388608
  constexpr int NW = (DMODEL * DMODEL) / 4;         // 262144
  int i = blockIdx.x * blockDim.x + threadIdx.x;
  const int stride = gridDim.x * blockDim.x;
  for (; i < NX + 4 * NW; i += stride) {
    const float* src; __bf16* dst; int idx;
    if (i < NX)            { src = x;  dst = xb;             idx = i; }
    else if (i < NX + NW)  { src = Wq; dst = Wqkvb;          idx = i - NX; }
    else if (i < NX + 2*NW){ src = Wk; dst = Wqkvb + 4*NW;   idx = i - NX - NW; }
    else if (i < NX + 3*NW){ src = Wv; dst = Wqkvb + 8*NW;   idx = i - NX - 2*NW; }
    else                   { src = Wo; dst = Wob;            idx = i - NX - 3*NW; }
    const float4 v = reinterpret_cast<const float4*>(src)[idx];
    bf16x4 o;
    o.x = (__bf16)v.x; o.y = (__bf16)v.y; o.z = (__bf16)v.z; o.w = (__bf16)v.w;
    reinterpret_cast<bf16x4*>(dst)[idx] = o;
  }
}

// ---------------------------------------------------------------- persistent 256x256 8-phase GEMM (NT)
// grid=256, 1 block/CU. Block = fixed bm (A panel), NCH bn-chunks as one virtual
// K-stream g in [0, NCH*16): k = (g&15)*64, bn = bn0 + (g>>4). Pipeline never
// drains across chunks; vmcnt(0) only at the final two boundaries of the block.
// Per-tile: 4 phases {reads; stage; bar; setprio; 16 MFMA; setprio; bar},
// stages P1:A-k1(g+1) P2:B-k1(g+1) P3:A-k0(g+2) P4:B-k0(g+2), boundary vmcnt(4).
// Ledger (verified): boundary(g-1->g) vmcnt(4) keeps {A,B}k0(g+1), forces
// {A,B}k1(g) [read P3(g)] and all older [k0(g), read P1(g)] landed.
template <int MODE>
__global__ __launch_bounds__(512, 1)
void gemm256_kernel(const __bf16* __restrict__ A, const __bf16* __restrict__ Bw,
                    const float* __restrict__ bias0, const float* __restrict__ bias1,
                    const float* __restrict__ bias2,
                    __bf16* __restrict__ outq, __bf16* __restrict__ outkT,
                    __bf16* __restrict__ outvT, float* __restrict__ outf) {
  extern __shared__ char smem[];
  constexpr int NBN = (MODE == 0) ? 12 : 4;  // N/256
  constexpr int NCH = NBN / 2;               // chunks per block (2 blocks per bm row)
  constexpr int GTOT = NCH * 16;

  const int blk = blockIdx.x;                // 256 blocks
  const int bm = blk >> 1;
  const int bn0 = (blk & 1) * NCH;
  const int m0 = bm * 256;

  const int tid = threadIdx.x;
  const int l = tid & 63;
  const int w = tid >> 6;
  const int wm = w >> 2, wn = w & 3;
  const int lrow = l & 15, g16 = l >> 4;
  const int arow = wm * 128 + lrow;
  const int brow = wn * 64 + lrow;

  // per-lane swizzled LDS read bases (invariant: +16/+64 rows keep the XOR bits)
  const int aoffA = (arow * 64 + g16 * 16) ^ (((arow >> 1) & 3) << 4);
  const int aoffB = (brow * 64 + g16 * 16) ^ (((brow >> 1) & 3) << 4);

  // per-lane staging geometry: Q = i*8192 + tid*16 (linear LDS dest),
  // logical Ls = Q ^ ((Q>>7)&3)<<4 -> source row/col
  const int tQ = tid * 16;
  int rowQ[2], colQ[2];
#pragma unroll
  for (int i = 0; i < 2; i++) {
    const int Q = i * 8192 + tQ;
    const int Ls = Q ^ (((Q >> 7) & 3) << 4);
    rowQ[i] = Ls >> 6; colQ[i] = (Ls & 63) >> 1;
  }
  const __bf16* baseA0 = A  + (size_t)(m0 + rowQ[0]) * 1024 + colQ[0];
  const __bf16* baseA1 = A  + (size_t)(m0 + rowQ[1]) * 1024 + colQ[1];
  const __bf16* baseB0 = Bw + (size_t)(bn0 * 256 + rowQ[0]) * 1024 + colQ[0];
  const __bf16* baseB1 = Bw + (size_t)(bn0 * 256 + rowQ[1]) * 1024 + colQ[1];

  auto stageA = [&](int kh, int g2) {
    char* lds0 = smem + ((g2 & 1) << 16) + (kh << 14);
    const int soff = (g2 & 15) * 64 + kh * 32;
    gload_lds16(baseA0 + soff, lds0 + tQ);
    gload_lds16(baseA1 + soff, lds0 + 8192 + tQ);
  };
  auto stageB = [&](int kh, int g2) {
    char* lds0 = smem + ((g2 & 1) << 16) + 32768 + (kh << 14);
    const size_t soff = (size_t)(((g2 >> 4) << 18) + (g2 & 15) * 64 + kh * 32);
    gload_lds16(baseB0 + soff, lds0 + tQ);
    gload_lds16(baseB1 + soff, lds0 + 8192 + tQ);
  };

  f32x4 acc[8][4] = {};

  // ---- prologue: k0(0), k1(0), k0(1); force first 8 (k0+k1 of tile 0)
  stageA(0, 0); stageB(0, 0);
  stageA(1, 0); stageB(1, 0);
  stageA(0, 1); stageB(0, 1);
  asm volatile("s_waitcnt vmcnt(4)" ::: "memory");
  __builtin_amdgcn_s_barrier();

  auto tile = [&](int g, int buf) {
    const int rb = buf << 16;
    // ---------------- P1: reads a0,b0 | stage A-k1(g+1) ----------------
    bf16x8 a0[4], b0[4];
#pragma unroll
    for (int mi = 0; mi < 4; mi++)
      a0[mi] = *reinterpret_cast<const bf16x8*>(smem + aoffA + rb + mi * 1024);
#pragma unroll
    for (int ni = 0; ni < 4; ni++)
      b0[ni] = *reinterpret_cast<const bf16x8*>(smem + aoffB + rb + 32768 + ni * 1024);
    if (g + 1 < GTOT) stageA(1, g + 1);
    asm volatile("" ::: "memory");
    __builtin_amdgcn_s_barrier();
    __builtin_amdgcn_s_setprio(1);
#pragma unroll
    for (int mi = 0; mi < 4; mi++)
#pragma unroll
      for (int ni = 0; ni < 4; ni++)
        acc[mi][ni] = __builtin_amdgcn_mfma_f32_16x16x32_bf16(a0[mi], b0[ni], acc[mi][ni], 0, 0, 0);
    __builtin_amdgcn_s_setprio(0);
    asm volatile("" ::: "memory");
    __builtin_amdgcn_s_barrier();
    // ---------------- P2: reads a1 | stage B-k1(g+1) ----------------
    bf16x8 a1[4];
#pragma unroll
    for (int mi = 0; mi < 4; mi++)
      a1[mi] = *reinterpret_cast<const bf16x8*>(smem + aoffA + rb + 4096 + mi * 1024);
    if (g + 1 < GTOT) stageB(1, g + 1);
    asm volatile("" ::: "memory");
    __builtin_amdgcn_s_barrier();
    __builtin_amdgcn_s_setprio(1);
#pragma unroll
    for (int mi = 0; mi < 4; mi++)
#pragma unroll
      for (int ni = 0; ni < 4; ni++)
        acc[4 + mi][ni] = __builtin_amdgcn_mfma_f32_16x16x32_bf16(a1[mi], b0[ni], acc[4 + mi][ni], 0, 0, 0);
    __builtin_amdgcn_s_setprio(0);
    asm volatile("" ::: "memory");
    __builtin_amdgcn_s_barrier();
    // ---------------- P3: reads a2,b1 | stage A-k0(g+2) ----------------
    bf16x8 a2[4], b1[4];
#pragma unroll
    for (int mi = 0; mi < 4; mi++)
      a2[mi] = *reinterpret_cast<const bf16x8*>(smem + aoffA + rb + 16384 + mi * 1024);
#pragma unroll
    for (int ni = 0; ni < 4; ni++)
      b1[ni] = *reinterpret_cast<const bf16x8*>(smem + aoffB + rb + 49152 + ni * 1024);
    if (g + 2 < GTOT) stageA(0, g + 2);
    asm volatile("" ::: "memory");
    __builtin_amdgcn_s_barrier();
    __builtin_amdgcn_s_setprio(1);
#pragma unroll
    for (int mi = 0; mi < 4; mi++)
#pragma unroll
      for (int ni = 0; ni < 4; ni++)
        acc[mi][ni] = __builtin_amdgcn_mfma_f32_16x16x32_bf16(a2[mi], b1[ni], acc[mi][ni], 0, 0, 0);
    __builtin_amdgcn_s_setprio(0);
    asm volatile("" ::: "memory");
    __builtin_amdgcn_s_barrier();
    // ---------------- P4: reads a3 | stage B-k0(g+2) ----------------
    bf16x8 a3[4];
#pragma unroll
    for (int mi = 0; mi < 4; mi++)
      a3[mi] = *reinterpret_cast<const bf16x8*>(smem + aoffA + rb + 16384 + 4096 + mi * 1024);
    if (g + 2 < GTOT) stageB(0, g + 2);
    asm volatile("" ::: "memory");
    __builtin_amdgcn_s_barrier();
    __builtin_amdgcn_s_setprio(1);
#pragma unroll
    for (int mi = 0; mi < 4; mi++)
#pragma unroll
      for (int ni = 0; ni < 4; ni++)
        acc[4 + mi][ni] = __builtin_amdgcn_mfma_f32_16x16x32_bf16(a3[mi], b1[ni], acc[4 + mi][ni], 0, 0, 0);
    __builtin_amdgcn_s_setprio(0);
    if (g < GTOT - 1) {
      if (g < GTOT - 2) asm volatile("s_waitcnt vmcnt(4)" ::: "memory");
      else              asm volatile("s_waitcnt vmcnt(0)" ::: "memory");
      __builtin_amdgcn_s_barrier();
    }
  };

  // epilogue for one finished chunk (C frag: col = l&15, row = g16*4 + r)
  auto epilogue = [&](int chunk) {
    const int j0 = (bn0 + chunk) * 256;
    const int jl0 = wn * 64 + lrow;
    if constexpr (MODE == 0) {
      const int sel = j0 >> 10;
      const int jb = j0 & 1023;
      const int jl = jb + jl0;
      const float* bias = (sel == 0) ? bias0 : ((sel == 1) ? bias1 : bias2);
      float bj[4];
#pragma unroll
      for (int ni = 0; ni < 4; ni++) bj[ni] = bias[jl + ni * 16];
      if (sel == 0) {
        __bf16* qb = outq + (size_t)(m0 + wm * 128 + g16 * 4) * 1024 + jl;
        const int mrel = (m0 & (NSEQ - 1)) + wm * 128 + g16 * 4;
#pragma unroll
        for (int mi = 0; mi < 8; mi++)
#pragma unroll
          for (int r = 0; r < 4; r++) {
            const float dec = __expf(-(float)((mrel + mi * 16 + r) & (NSEQ - 1)) * (1.0f / NSEQ));
#pragma unroll
            for (int ni = 0; ni < 4; ni++)
              qb[mi * 16384 + r * 1024 + ni * 16] =
                  (__bf16)(fmaxf(acc[mi][ni][r] + bj[ni], 0.f) * dec);
          }
      } else {
        const int bidx = m0 >> 9;                       // constant per block
        const int n0b = (m0 & (NSEQ - 1)) + wm * 128 + g16 * 4;
        __bf16* dst = (sel == 1) ? outkT : outvT;
        __bf16* cp[4];
#pragma unroll
        for (int ni = 0; ni < 4; ni++) {
          const int j = jl + ni * 16;
          cp[ni] = dst + (size_t)((bidx * NHEAD + (j >> 6)) * DHEAD + (j & 63)) * NSEQ + n0b;
        }
#pragma unroll
        for (int mi = 0; mi < 8; mi++) {
          float dec4[4];
          if (sel == 1) {
#pragma unroll
            for (int r = 0; r < 4; r++)
              dec4[r] = __expf(-(float)(n0b + mi * 16 + r) * (1.0f / NSEQ));
          }
#pragma unroll
          for (int ni = 0; ni < 4; ni++) {
            bf16x4 pk;
#pragma unroll
            for (int r = 0; r < 4; r++) {
              float val = acc[mi][ni][r] + bj[ni];
              if (sel == 1) val = fmaxf(val, 0.f) * dec4[r];
              pk[r] = (__bf16)val;
            }
            *reinterpret_cast<bf16x4*>(cp[ni] + mi * 16) = pk;
          }
        }
      }
    } else {
      const int jl = j0 + jl0;
      float bj[4];
#pragma unroll
      for (int ni = 0; ni < 4; ni++) bj[ni] = bias0[jl + ni * 16];
      float* fb = outf + (size_t)(m0 + wm * 128 + g16 * 4) * 1024 + jl;
#pragma unroll
      for (int mi = 0; mi < 8; mi++)
#pragma unroll
        for (int ni = 0; ni < 4; ni++)
#pragma unroll
          for (int r = 0; r < 4; r++)
            fb[mi * 16384 + r * 1024 + ni * 16] = acc[mi][ni][r] + bj[ni];
    }
    // reset accumulators for next chunk
#pragma unroll
    for (int mi = 0; mi < 8; mi++)
#pragma unroll
      for (int ni = 0; ni < 4; ni++)
        acc[mi][ni] = f32x4{0.f, 0.f, 0.f, 0.f};
  };

  for (int gp = 0; gp < GTOT; gp += 2) {
    tile(gp, 0);
    tile(gp + 1, 1);
    if (((gp + 1) & 15) == 15) epilogue(gp >> 4);
  }
}

// ---------------------------------------------------------------- attention core
// one block per (b,h); 256 threads = 4 waves.
__global__ void attn_kernel(const __bf16* __restrict__ qf, const __bf16* __restrict__ kfT,
                            const __bf16* __restrict__ vT, __bf16* __restrict__ attn) {
  const int bh = blockIdx.x;                 // b*16 + h
  const int b = bh >> 4, h = bh & 15;
  const __bf16* kT = kfT + (size_t)bh * DHEAD * NSEQ;
  const __bf16* vTp = vT + (size_t)bh * DHEAD * NSEQ;
  const __bf16* qp = qf + (size_t)b * NSEQ * DMODEL + h * DHEAD;
  __bf16* op = attn + (size_t)b * NSEQ * DMODEL + h * DHEAD;

  const int tid = threadIdx.x;
  const int l = tid & 63;
  const int w = tid >> 6;
  const int lrow = l & 15, lk = (l >> 4) * 8;

  __shared__ __bf16 KVT[64][88];
  __shared__ float Ksum[64];
  __shared__ float ksum_part[4][64];
  __shared__ float denom[512];

  // ---- KV[d,e] = sum_n kfT[d,n]*vT[e,n]; wave w owns d in [w*16, w*16+16)
  {
    f32x4 kv[4] = {};
    const int arow = w * 16 + lrow;
    for (int kk = 0; kk < NSEQ; kk += 32) {
      bf16x8 a = *reinterpret_cast<const bf16x8*>(&kT[(size_t)arow * NSEQ + kk + lk]);
#pragma unroll
      for (int ni = 0; ni < 4; ni++) {
        bf16x8 bv = *reinterpret_cast<const bf16x8*>(&vTp[(size_t)(ni * 16 + lrow) * NSEQ + kk + lk]);
        kv[ni] = __builtin_amdgcn_mfma_f32_16x16x32_bf16(a, bv, kv[ni], 0, 0, 0);
      }
    }
    const int d0 = w * 16 + ((l >> 4) << 2);
#pragma unroll
    for (int ni = 0; ni < 4; ni++) {
      const int e = ni * 16 + lrow;
      bf16x4 pk;
#pragma unroll
      for (int r = 0; r < 4; r++) pk[r] = (__bf16)kv[ni][r];
      *reinterpret_cast<bf16x4*>(&KVT[e][d0]) = pk;
    }
  }

  // ---- Ksum[d] = sum_n kfT[d,n]
  {
    const int d = tid & 63, part = tid >> 6;
    float s = 0.f;
    for (int n = part * 128; n < part * 128 + 128; n += 8) {
      bf16x8 kv8 = *reinterpret_cast<const bf16x8*>(&kT[(size_t)d * NSEQ + n]);
#pragma unroll
      for (int j = 0; j < 8; j++) s += (float)kv8[j];
    }
    ksum_part[part][d] = s;
  }
  __syncthreads();
  if (tid < 64)
    Ksum[tid] = ksum_part[0][tid] + ksum_part[1][tid] + ksum_part[2][tid] + ksum_part[3][tid];
  __syncthreads();

  // ---- denom[n] = qf[n,:] . Ksum + eps
  for (int n = tid; n < NSEQ; n += 256) {
    float s = 0.f;
#pragma unroll
    for (int d = 0; d < DHEAD; d += 8) {
      bf16x8 q8 = *reinterpret_cast<const bf16x8*>(&qp[(size_t)n * DMODEL + d]);
#pragma unroll
      for (int j = 0; j < 8; j++) s += (float)q8[j] * Ksum[d + j];
    }
    denom[n] = s + 1e-6f;
  }
  __syncthreads();

  // ---- out[n,e] = (sum_d qf[n,d]*KVT[e,d]) / denom[n]
  for (int t = 0; t < 8; t++) {
    const int nrow = t * 64 + w * 16 + lrow;
    bf16x8 a0 = *reinterpret_cast<const bf16x8*>(&qp[(size_t)nrow * DMODEL + lk]);
    bf16x8 a1 = *reinterpret_cast<const bf16x8*>(&qp[(size_t)nrow * DMODEL + 32 + lk]);
    f32x4 o[4] = {};
#pragma unroll
    for (int ni = 0; ni < 4; ni++) {
      bf16x8 b0 = *reinterpret_cast<const bf16x8*>(&KVT[ni * 16 + lrow][lk]);
      bf16x8 b1 = *reinterpret_cast<const bf16x8*>(&KVT[ni * 16 + lrow][32 + lk]);
      o[ni] = __builtin_amdgcn_mfma_f32_16x16x32_bf16(a0, b0, o[ni], 0, 0, 0);
      o[ni] = __builtin_amdgcn_mfma_f32_16x16x32_bf16(a1, b1, o[ni], 0, 0, 0);
    }
    const int n0 = t * 64 + w * 16 + ((l >> 4) << 2);
#pragma unroll
    for (int ni = 0; ni < 4; ni++) {
      const int e = ni * 16 + lrow;
#pragma unroll
      for (int r = 0; r < 4; r++)
        op[(size_t)(n0 + r) * DMODEL + e] = (__bf16)(o[ni][r] / denom[n0 + r]);
    }
  }
}

// ---------------------------------------------------------------- launch
extern "C" void kernel_launch(void* const* d_in, const int* in_sizes, int n_in,
                              void* d_out, int out_size, void* d_ws, size_t ws_size,
                              hipStream_t stream) {
  (void)in_sizes; (void)n_in; (void)out_size; (void)ws_size;
  const float* x  = (const float*)d_in[0];
  const float* Wq = (const float*)d_in[1];
  const float* bq = (const float*)d_in[2];
  const float* Wk = (const float*)d_in[3];
  const float* bk = (const float*)d_in[4];
  const float* Wv = (const float*)d_in[5];
  const float* bv = (const float*)d_in[6];
  const float* Wo = (const float*)d_in[7];
  const float* bo = (const float*)d_in[8];
  float* out = (float*)d_out;

  char* ws = (char*)d_ws;
  __bf16* xb    = (__bf16*)(ws);                    // 64 MB  (reused as attn output)
  __bf16* qf    = (__bf16*)(ws + 67108864);         // 64 MB
  __bf16* kfT   = (__bf16*)(ws + 134217728);        // 64 MB
  __bf16* vT    = (__bf16*)(ws + 201326592);        // 64 MB
  __bf16* Wqkvb = (__bf16*)(ws + 268435456);        // 6 MB
  __bf16* Wob   = (__bf16*)(ws + 274726912);        // 2 MB
  __bf16* attnb = xb;                               // alias: xb dead after QKV GEMM

  cvt_all_kernel<<<4096, 256, 0, stream>>>(x, Wq, Wk, Wv, Wo, xb, Wqkvb, Wob);

  gemm256_kernel<0><<<256, 512, 131072, stream>>>(xb, Wqkvb, bq, bk, bv,
                                                  qf, kfT, vT, nullptr);
  attn_kernel<<<NBATCH * NHEAD, 256, 0, stream>>>(qf, kfT, vT, attnb);
  gemm256_kernel<1><<<256, 512, 131072, stream>>>(attnb, Wob, bo, nullptr, nullptr,
                                                  nullptr, nullptr, nullptr, out);
}

// Round 6
// 583.923 us; speedup vs baseline: 7.3695x; 7.3695x over previous
//
#include <hip/hip_runtime.h>
#include <hip/hip_bf16.h>

typedef __attribute__((ext_vector_type(8))) __bf16 bf16x8;
typedef __attribute__((ext_vector_type(4))) __bf16 bf16x4;
typedef __attribute__((ext_vector_type(4))) float f32x4;

#define NBATCH 64
#define NSEQ   512
#define DMODEL 1024
#define NHEAD  16
#define DHEAD  64
#define MROWS  (NBATCH * NSEQ)   // 32768

static __device__ __forceinline__ void gload_lds16(const void* gp, void* lp) {
  __builtin_amdgcn_global_load_lds(
      (__attribute__((address_space(1))) const void*)gp,
      (__attribute__((address_space(3))) void*)lp,
      16, 0, 0);
}

// ---------------------------------------------------------------- merged convert
__global__ void cvt_all_kernel(const float* __restrict__ x, const float* __restrict__ Wq,
                               const float* __restrict__ Wk, const float* __restrict__ Wv,
                               const float* __restrict__ Wo,
                               __bf16* __restrict__ xb, __bf16* __restrict__ Wqkvb,
                               __bf16* __restrict__ Wob) {
  constexpr int NX = (MROWS * DMODEL) / 4;          // 8388608
  constexpr int NW = (DMODEL * DMODEL) / 4;         // 262144
  int i = blockIdx.x * blockDim.x + threadIdx.x;
  const int stride = gridDim.x * blockDim.x;
  for (; i < NX + 4 * NW; i += stride) {
    const float* src; __bf16* dst; int idx;
    if (i < NX)            { src = x;  dst = xb;             idx = i; }
    else if (i < NX + NW)  { src = Wq; dst = Wqkvb;          idx = i - NX; }
    else if (i < NX + 2*NW){ src = Wk; dst = Wqkvb + 4*NW;   idx = i - NX - NW; }
    else if (i < NX + 3*NW){ src = Wv; dst = Wqkvb + 8*NW;   idx = i - NX - 2*NW; }
    else                   { src = Wo; dst = Wob;            idx = i - NX - 3*NW; }
    const float4 v = reinterpret_cast<const float4*>(src)[idx];
    bf16x4 o;
    o.x = (__bf16)v.x; o.y = (__bf16)v.y; o.z = (__bf16)v.z; o.w = (__bf16)v.w;
    reinterpret_cast<bf16x4*>(dst)[idx] = o;
  }
}

// ---------------------------------------------------------------- persistent GEMM helpers
struct Bases {
  const __bf16* A0; const __bf16* A1;
  const __bf16* B0; const __bf16* B1;
};

static __device__ __forceinline__ void stage_A(char* smem, const Bases& b, int tQ,
                                               int kh, int g2) {
  char* lds0 = smem + ((g2 & 1) << 16) + (kh << 14);
  const int soff = (g2 & 15) * 64 + kh * 32;
  gload_lds16(b.A0 + soff, lds0 + tQ);
  gload_lds16(b.A1 + soff, lds0 + 8192 + tQ);
}

static __device__ __forceinline__ void stage_B(char* smem, const Bases& b, int tQ,
                                               int kh, int g2) {
  char* lds0 = smem + ((g2 & 1) << 16) + 32768 + (kh << 14);
  const int soff = ((g2 >> 4) << 18) + (g2 & 15) * 64 + kh * 32;
  gload_lds16(b.B0 + soff, lds0 + tQ);
  gload_lds16(b.B1 + soff, lds0 + 8192 + tQ);
}

// one K-tile (64 deep), 4 phases; stages P1:A-k1(g+1) P2:B-k1(g+1)
// P3:A-k0(g+2) P4:B-k0(g+2); boundary vmcnt(4) (vmcnt(0) at g==GTOT-2).
static __device__ __forceinline__ void do_tile(char* smem, f32x4 (&acc)[8][4],
                                               const Bases& bs, int tQ,
                                               int aoffA, int aoffB,
                                               int g, int buf, int GTOT) {
  const int rb = buf << 16;
  // ---------------- P1: reads a0,b0 | stage A-k1(g+1) ----------------
  bf16x8 a0[4], b0[4];
#pragma unroll
  for (int mi = 0; mi < 4; mi++)
    a0[mi] = *reinterpret_cast<const bf16x8*>(smem + aoffA + rb + mi * 1024);
#pragma unroll
  for (int ni = 0; ni < 4; ni++)
    b0[ni] = *reinterpret_cast<const bf16x8*>(smem + aoffB + rb + 32768 + ni * 1024);
  if (g + 1 < GTOT) stage_A(smem, bs, tQ, 1, g + 1);
  asm volatile("" ::: "memory");
  __builtin_amdgcn_s_barrier();
  __builtin_amdgcn_s_setprio(1);
#pragma unroll
  for (int mi = 0; mi < 4; mi++)
#pragma unroll
    for (int ni = 0; ni < 4; ni++)
      acc[mi][ni] = __builtin_amdgcn_mfma_f32_16x16x32_bf16(a0[mi], b0[ni], acc[mi][ni], 0, 0, 0);
  __builtin_amdgcn_s_setprio(0);
  asm volatile("" ::: "memory");
  __builtin_amdgcn_s_barrier();
  // ---------------- P2: reads a1 | stage B-k1(g+1) ----------------
  bf16x8 a1[4];
#pragma unroll
  for (int mi = 0; mi < 4; mi++)
    a1[mi] = *reinterpret_cast<const bf16x8*>(smem + aoffA + rb + 4096 + mi * 1024);
  if (g + 1 < GTOT) stage_B(smem, bs, tQ, 1, g + 1);
  asm volatile("" ::: "memory");
  __builtin_amdgcn_s_barrier();
  __builtin_amdgcn_s_setprio(1);
#pragma unroll
  for (int mi = 0; mi < 4; mi++)
#pragma unroll
    for (int ni = 0; ni < 4; ni++)
      acc[4 + mi][ni] = __builtin_amdgcn_mfma_f32_16x16x32_bf16(a1[mi], b0[ni], acc[4 + mi][ni], 0, 0, 0);
  __builtin_amdgcn_s_setprio(0);
  asm volatile("" ::: "memory");
  __builtin_amdgcn_s_barrier();
  // ---------------- P3: reads a2,b1 | stage A-k0(g+2) ----------------
  bf16x8 a2[4], b1[4];
#pragma unroll
  for (int mi = 0; mi < 4; mi++)
    a2[mi] = *reinterpret_cast<const bf16x8*>(smem + aoffA + rb + 16384 + mi * 1024);
#pragma unroll
  for (int ni = 0; ni < 4; ni++)
    b1[ni] = *reinterpret_cast<const bf16x8*>(smem + aoffB + rb + 49152 + ni * 1024);
  if (g + 2 < GTOT) stage_A(smem, bs, tQ, 0, g + 2);
  asm volatile("" ::: "memory");
  __builtin_amdgcn_s_barrier();
  __builtin_amdgcn_s_setprio(1);
#pragma unroll
  for (int mi = 0; mi < 4; mi++)
#pragma unroll
    for (int ni = 0; ni < 4; ni++)
      acc[mi][ni] = __builtin_amdgcn_mfma_f32_16x16x32_bf16(a2[mi], b1[ni], acc[mi][ni], 0, 0, 0);
  __builtin_amdgcn_s_setprio(0);
  asm volatile("" ::: "memory");
  __builtin_amdgcn_s_barrier();
  // ---------------- P4: reads a3 | stage B-k0(g+2) ----------------
  bf16x8 a3[4];
#pragma unroll
  for (int mi = 0; mi < 4; mi++)
    a3[mi] = *reinterpret_cast<const bf16x8*>(smem + aoffA + rb + 20480 + mi * 1024);
  if (g + 2 < GTOT) stage_B(smem, bs, tQ, 0, g + 2);
  asm volatile("" ::: "memory");
  __builtin_amdgcn_s_barrier();
  __builtin_amdgcn_s_setprio(1);
#pragma unroll
  for (int mi = 0; mi < 4; mi++)
#pragma unroll
    for (int ni = 0; ni < 4; ni++)
      acc[4 + mi][ni] = __builtin_amdgcn_mfma_f32_16x16x32_bf16(a3[mi], b1[ni], acc[4 + mi][ni], 0, 0, 0);
  __builtin_amdgcn_s_setprio(0);
  if (g < GTOT - 1) {
    if (g < GTOT - 2) asm volatile("s_waitcnt vmcnt(4)" ::: "memory");
    else              asm volatile("s_waitcnt vmcnt(0)" ::: "memory");
    __builtin_amdgcn_s_barrier();
  }
}

// ---------------------------------------------------------------- persistent 256x256 GEMM (NT)
// grid=256, 1 block/CU. Block = fixed bm (A panel), NCH bn-chunks as one
// virtual K-stream g in [0, NCH*16): k = (g&15)*64, bn = bn0 + (g>>4).
// Pipeline never drains across chunks; epilogue runs between chunks with the
// next chunk's first half-tile already in flight.
template <int MODE>
__global__ __launch_bounds__(512, 1)
void gemm256_kernel(const __bf16* __restrict__ A, const __bf16* __restrict__ Bw,
                    const float* __restrict__ bias0, const float* __restrict__ bias1,
                    const float* __restrict__ bias2,
                    __bf16* __restrict__ outq, __bf16* __restrict__ outkT,
                    __bf16* __restrict__ outvT, float* __restrict__ outf) {
  extern __shared__ char smem[];
  constexpr int NBN = (MODE == 0) ? 12 : 4;  // N/256
  constexpr int NCH = NBN / 2;               // chunks per block
  constexpr int GTOT = NCH * 16;

  const int blk = blockIdx.x;                // 256 blocks
  const int bm = blk >> 1;
  const int bn0 = (blk & 1) * NCH;
  const int m0 = bm * 256;

  const int tid = threadIdx.x;
  const int l = tid & 63;
  const int w = tid >> 6;
  const int wm = w >> 2, wn = w & 3;
  const int lrow = l & 15, g16 = l >> 4;
  const int arow = wm * 128 + lrow;
  const int brow = wn * 64 + lrow;

  // per-lane swizzled LDS read bases (XOR bits invariant under +16/+64 rows)
  const int aoffA = (arow * 64 + g16 * 16) ^ (((arow >> 1) & 3) << 4);
  const int aoffB = (brow * 64 + g16 * 16) ^ (((brow >> 1) & 3) << 4);

  // per-lane staging geometry
  const int tQ = tid * 16;
  int rowQ[2], colQ[2];
#pragma unroll
  for (int i = 0; i < 2; i++) {
    const int Q = i * 8192 + tQ;
    const int Ls = Q ^ (((Q >> 7) & 3) << 4);
    rowQ[i] = Ls >> 6; colQ[i] = (Ls & 63) >> 1;
  }
  Bases bs;
  bs.A0 = A  + (size_t)(m0 + rowQ[0]) * 1024 + colQ[0];
  bs.A1 = A  + (size_t)(m0 + rowQ[1]) * 1024 + colQ[1];
  bs.B0 = Bw + (size_t)(bn0 * 256 + rowQ[0]) * 1024 + colQ[0];
  bs.B1 = Bw + (size_t)(bn0 * 256 + rowQ[1]) * 1024 + colQ[1];

  f32x4 acc[8][4] = {};

  // ---- prologue: k0(0), k1(0), k0(1); force tile0, keep 4 in flight
  stage_A(smem, bs, tQ, 0, 0); stage_B(smem, bs, tQ, 0, 0);
  stage_A(smem, bs, tQ, 1, 0); stage_B(smem, bs, tQ, 1, 0);
  stage_A(smem, bs, tQ, 0, 1); stage_B(smem, bs, tQ, 0, 1);
  asm volatile("s_waitcnt vmcnt(4)" ::: "memory");
  __builtin_amdgcn_s_barrier();

  for (int g = 0; g < GTOT; g += 2) {
    do_tile(smem, acc, bs, tQ, aoffA, aoffB, g, 0, GTOT);
    do_tile(smem, acc, bs, tQ, aoffA, aoffB, g + 1, 1, GTOT);
    if (((g + 1) & 15) == 15) {
      // ---------------- epilogue for chunk (g>>4), inline ----------------
      const int chunk = g >> 4;
      const int j0 = (bn0 + chunk) * 256;
      const int jl0 = wn * 64 + lrow;
      if constexpr (MODE == 0) {
        const int sel = j0 >> 10;
        const int jb = j0 & 1023;
        const int jl = jb + jl0;
        const float* bias = (sel == 0) ? bias0 : ((sel == 1) ? bias1 : bias2);
        float bj[4];
#pragma unroll
        for (int ni = 0; ni < 4; ni++) bj[ni] = bias[jl + ni * 16];
        if (sel == 0) {
          __bf16* qb = outq + (size_t)(m0 + wm * 128 + g16 * 4) * 1024 + jl;
          const int mrel = (m0 & (NSEQ - 1)) + wm * 128 + g16 * 4;
#pragma unroll
          for (int mi = 0; mi < 8; mi++)
#pragma unroll
            for (int r = 0; r < 4; r++) {
              const float dec = __expf(-(float)(mrel + mi * 16 + r) * (1.0f / NSEQ));
#pragma unroll
              for (int ni = 0; ni < 4; ni++)
                qb[mi * 16384 + r * 1024 + ni * 16] =
                    (__bf16)(fmaxf(acc[mi][ni][r] + bj[ni], 0.f) * dec);
            }
        } else {
          const int bidx = m0 >> 9;
          const int n0b = (m0 & (NSEQ - 1)) + wm * 128 + g16 * 4;
          __bf16* dst = (sel == 1) ? outkT : outvT;
          __bf16* cp[4];
#pragma unroll
          for (int ni = 0; ni < 4; ni++) {
            const int j = jl + ni * 16;
            cp[ni] = dst + (size_t)((bidx * NHEAD + (j >> 6)) * DHEAD + (j & 63)) * NSEQ + n0b;
          }
#pragma unroll
          for (int mi = 0; mi < 8; mi++) {
            float dec4[4];
            if (sel == 1) {
#pragma unroll
              for (int r = 0; r < 4; r++)
                dec4[r] = __expf(-(float)(n0b + mi * 16 + r) * (1.0f / NSEQ));
            }
#pragma unroll
            for (int ni = 0; ni < 4; ni++) {
              bf16x4 pk;
#pragma unroll
              for (int r = 0; r < 4; r++) {
                float val = acc[mi][ni][r] + bj[ni];
                if (sel == 1) val = fmaxf(val, 0.f) * dec4[r];
                pk[r] = (__bf16)val;
              }
              *reinterpret_cast<bf16x4*>(cp[ni] + mi * 16) = pk;
            }
          }
        }
      } else {
        const int jl = j0 + jl0;
        float bj[4];
#pragma unroll
        for (int ni = 0; ni < 4; ni++) bj[ni] = bias0[jl + ni * 16];
        float* fb = outf + (size_t)(m0 + wm * 128 + g16 * 4) * 1024 + jl;
#pragma unroll
        for (int mi = 0; mi < 8; mi++)
#pragma unroll
          for (int ni = 0; ni < 4; ni++)
#pragma unroll
            for (int r = 0; r < 4; r++)
              fb[mi * 16384 + r * 1024 + ni * 16] = acc[mi][ni][r] + bj[ni];
      }
      // reset accumulators for next chunk
#pragma unroll
      for (int mi = 0; mi < 8; mi++)
#pragma unroll
        for (int ni = 0; ni < 4; ni++)
          acc[mi][ni] = f32x4{0.f, 0.f, 0.f, 0.f};
    }
  }
}

// ---------------------------------------------------------------- attention core
// one block per (b,h); 256 threads = 4 waves.
__global__ void attn_kernel(const __bf16* __restrict__ qf, const __bf16* __restrict__ kfT,
                            const __bf16* __restrict__ vT, __bf16* __restrict__ attn) {
  const int bh = blockIdx.x;                 // b*16 + h
  const int b = bh >> 4, h = bh & 15;
  const __bf16* kT = kfT + (size_t)bh * DHEAD * NSEQ;
  const __bf16* vTp = vT + (size_t)bh * DHEAD * NSEQ;
  const __bf16* qp = qf + (size_t)b * NSEQ * DMODEL + h * DHEAD;
  __bf16* op = attn + (size_t)b * NSEQ * DMODEL + h * DHEAD;

  const int tid = threadIdx.x;
  const int l = tid & 63;
  const int w = tid >> 6;
  const int lrow = l & 15, lk = (l >> 4) * 8;

  __shared__ __bf16 KVT[64][88];
  __shared__ float Ksum[64];
  __shared__ float ksum_part[4][64];
  __shared__ float denom[512];

  // ---- KV[d,e] = sum_n kfT[d,n]*vT[e,n]; wave w owns d in [w*16, w*16+16)
  {
    f32x4 kv[4] = {};
    const int arow = w * 16 + lrow;
    for (int kk = 0; kk < NSEQ; kk += 32) {
      bf16x8 a = *reinterpret_cast<const bf16x8*>(&kT[(size_t)arow * NSEQ + kk + lk]);
#pragma unroll
      for (int ni = 0; ni < 4; ni++) {
        bf16x8 bv = *reinterpret_cast<const bf16x8*>(&vTp[(size_t)(ni * 16 + lrow) * NSEQ + kk + lk]);
        kv[ni] = __builtin_amdgcn_mfma_f32_16x16x32_bf16(a, bv, kv[ni], 0, 0, 0);
      }
    }
    const int d0 = w * 16 + ((l >> 4) << 2);
#pragma unroll
    for (int ni = 0; ni < 4; ni++) {
      const int e = ni * 16 + lrow;
      bf16x4 pk;
#pragma unroll
      for (int r = 0; r < 4; r++) pk[r] = (__bf16)kv[ni][r];
      *reinterpret_cast<bf16x4*>(&KVT[e][d0]) = pk;
    }
  }

  // ---- Ksum[d] = sum_n kfT[d,n]
  {
    const int d = tid & 63, part = tid >> 6;
    float s = 0.f;
    for (int n = part * 128; n < part * 128 + 128; n += 8) {
      bf16x8 kv8 = *reinterpret_cast<const bf16x8*>(&kT[(size_t)d * NSEQ + n]);
#pragma unroll
      for (int j = 0; j < 8; j++) s += (float)kv8[j];
    }
    ksum_part[part][d] = s;
  }
  __syncthreads();
  if (tid < 64)
    Ksum[tid] = ksum_part[0][tid] + ksum_part[1][tid] + ksum_part[2][tid] + ksum_part[3][tid];
  __syncthreads();

  // ---- denom[n] = qf[n,:] . Ksum + eps
  for (int n = tid; n < NSEQ; n += 256) {
    float s = 0.f;
#pragma unroll
    for (int d = 0; d < DHEAD; d += 8) {
      bf16x8 q8 = *reinterpret_cast<const bf16x8*>(&qp[(size_t)n * DMODEL + d]);
#pragma unroll
      for (int j = 0; j < 8; j++) s += (float)q8[j] * Ksum[d + j];
    }
    denom[n] = s + 1e-6f;
  }
  __syncthreads();

  // ---- out[n,e] = (sum_d qf[n,d]*KVT[e,d]) / denom[n]
  for (int t = 0; t < 8; t++) {
    const int nrow = t * 64 + w * 16 + lrow;
    bf16x8 a0 = *reinterpret_cast<const bf16x8*>(&qp[(size_t)nrow * DMODEL + lk]);
    bf16x8 a1 = *reinterpret_cast<const bf16x8*>(&qp[(size_t)nrow * DMODEL + 32 + lk]);
    f32x4 o[4] = {};
#pragma unroll
    for (int ni = 0; ni < 4; ni++) {
      bf16x8 b0 = *reinterpret_cast<const bf16x8*>(&KVT[ni * 16 + lrow][lk]);
      bf16x8 b1 = *reinterpret_cast<const bf16x8*>(&KVT[ni * 16 + lrow][32 + lk]);
      o[ni] = __builtin_amdgcn_mfma_f32_16x16x32_bf16(a0, b0, o[ni], 0, 0, 0);
      o[ni] = __builtin_amdgcn_mfma_f32_16x16x32_bf16(a1, b1, o[ni], 0, 0, 0);
    }
    const int n0 = t * 64 + w * 16 + ((l >> 4) << 2);
#pragma unroll
    for (int ni = 0; ni < 4; ni++) {
      const int e = ni * 16 + lrow;
#pragma unroll
      for (int r = 0; r < 4; r++)
        op[(size_t)(n0 + r) * DMODEL + e] = (__bf16)(o[ni][r] / denom[n0 + r]);
    }
  }
}

// ---------------------------------------------------------------- launch
extern "C" void kernel_launch(void* const* d_in, const int* in_sizes, int n_in,
                              void* d_out, int out_size, void* d_ws, size_t ws_size,
                              hipStream_t stream) {
  (void)in_sizes; (void)n_in; (void)out_size; (void)ws_size;
  const float* x  = (const float*)d_in[0];
  const float* Wq = (const float*)d_in[1];
  const float* bq = (const float*)d_in[2];
  const float* Wk = (const float*)d_in[3];
  const float* bk = (const float*)d_in[4];
  const float* Wv = (const float*)d_in[5];
  const float* bv = (const float*)d_in[6];
  const float* Wo = (const float*)d_in[7];
  const float* bo = (const float*)d_in[8];
  float* out = (float*)d_out;

  char* ws = (char*)d_ws;
  __bf16* xb    = (__bf16*)(ws);                    // 64 MB  (reused as attn output)
  __bf16* qf    = (__bf16*)(ws + 67108864);         // 64 MB
  __bf16* kfT   = (__bf16*)(ws + 134217728);        // 64 MB
  __bf16* vT    = (__bf16*)(ws + 201326592);        // 64 MB
  __bf16* Wqkvb = (__bf16*)(ws + 268435456);        // 6 MB
  __bf16* Wob   = (__bf16*)(ws + 274726912);        // 2 MB
  __bf16* attnb = xb;                               // alias: xb dead after QKV GEMM

  cvt_all_kernel<<<4096, 256, 0, stream>>>(x, Wq, Wk, Wv, Wo, xb, Wqkvb, Wob);

  gemm256_kernel<0><<<256, 512, 131072, stream>>>(xb, Wqkvb, bq, bk, bv,
                                                  qf, kfT, vT, nullptr);
  attn_kernel<<<NBATCH * NHEAD, 256, 0, stream>>>(qf, kfT, vT, attnb);
  gemm256_kernel<1><<<256, 512, 131072, stream>>>(attnb, Wob, bo, nullptr, nullptr,
                                                  nullptr, nullptr, nullptr, out);
}

// Round 7
// 418.573 us; speedup vs baseline: 10.2807x; 1.3950x over previous
//
#include <hip/hip_runtime.h>
#include <hip/hip_bf16.h>

typedef __attribute__((ext_vector_type(8))) __bf16 bf16x8;
typedef __attribute__((ext_vector_type(4))) __bf16 bf16x4;
typedef __attribute__((ext_vector_type(4))) float f32x4;

#define NBATCH 64
#define NSEQ   512
#define DMODEL 1024
#define NHEAD  16
#define DHEAD  64
#define MROWS  (NBATCH * NSEQ)   // 32768

static __device__ __forceinline__ void gload_lds16(const void* gp, void* lp) {
  __builtin_amdgcn_global_load_lds(
      (__attribute__((address_space(1))) const void*)gp,
      (__attribute__((address_space(3))) void*)lp,
      16, 0, 0);
}

// ---------------------------------------------------------------- merged convert
__global__ void cvt_all_kernel(const float* __restrict__ x, const float* __restrict__ Wq,
                               const float* __restrict__ Wk, const float* __restrict__ Wv,
                               const float* __restrict__ Wo,
                               __bf16* __restrict__ xb, __bf16* __restrict__ Wqkvb,
                               __bf16* __restrict__ Wob) {
  constexpr int NX = (MROWS * DMODEL) / 4;          // 8388608
  constexpr int NW = (DMODEL * DMODEL) / 4;         // 262144
  int i = blockIdx.x * blockDim.x + threadIdx.x;
  const int stride = gridDim.x * blockDim.x;
  for (; i < NX + 4 * NW; i += stride) {
    const float* src; __bf16* dst; int idx;
    if (i < NX)            { src = x;  dst = xb;             idx = i; }
    else if (i < NX + NW)  { src = Wq; dst = Wqkvb;          idx = i - NX; }
    else if (i < NX + 2*NW){ src = Wk; dst = Wqkvb + 4*NW;   idx = i - NX - NW; }
    else if (i < NX + 3*NW){ src = Wv; dst = Wqkvb + 8*NW;   idx = i - NX - 2*NW; }
    else                   { src = Wo; dst = Wob;            idx = i - NX - 3*NW; }
    const float4 v = reinterpret_cast<const float4*>(src)[idx];
    bf16x4 o;
    o.x = (__bf16)v.x; o.y = (__bf16)v.y; o.z = (__bf16)v.z; o.w = (__bf16)v.w;
    reinterpret_cast<bf16x4*>(dst)[idx] = o;
  }
}

// ---------------------------------------------------------------- GEMM helpers
struct Bases {
  const __bf16* A0; const __bf16* A1;
  const __bf16* B0; const __bf16* B1;
};

// stage one 16KB half-panel (2 gloads/thread); lds dest linear, source pre-swizzled
static __device__ __forceinline__ void stage_half(char* smem, const __bf16* p0,
                                                  const __bf16* p1, int tQ,
                                                  int ldsbase, int kh, int T) {
  char* lds0 = smem + ((T & 1) << 16) + ldsbase + (kh << 14);
  const int soff = T * 64 + kh * 32;
  gload_lds16(p0 + soff, lds0 + tQ);
  gload_lds16(p1 + soff, lds0 + 8192 + tQ);
}

// one K-tile (64 deep), 4 phases; stages P1:A-k1(T+1) P2:B-k1(T+1)
// P3:A-k0(T+2) P4:B-k0(T+2); boundary vmcnt(4) (vmcnt(0) at T==NT-2).
static __device__ __forceinline__ void do_tile(char* smem, f32x4 (&acc)[8][4],
                                               const Bases& bs, int tQ,
                                               int aoffA, int aoffB,
                                               int T, int buf, int NT) {
  const int rb = buf << 16;
  // ---------------- P1: reads a0,b0 | stage A-k1(T+1) ----------------
  bf16x8 a0[4], b0[4];
#pragma unroll
  for (int mi = 0; mi < 4; mi++)
    a0[mi] = *reinterpret_cast<const bf16x8*>(smem + aoffA + rb + mi * 1024);
#pragma unroll
  for (int ni = 0; ni < 4; ni++)
    b0[ni] = *reinterpret_cast<const bf16x8*>(smem + aoffB + rb + 32768 + ni * 1024);
  if (T + 1 < NT) stage_half(smem, bs.A0, bs.A1, tQ, 0, 1, T + 1);
  asm volatile("" ::: "memory");
  __builtin_amdgcn_s_barrier();
  __builtin_amdgcn_s_setprio(1);
#pragma unroll
  for (int mi = 0; mi < 4; mi++)
#pragma unroll
    for (int ni = 0; ni < 4; ni++)
      acc[mi][ni] = __builtin_amdgcn_mfma_f32_16x16x32_bf16(a0[mi], b0[ni], acc[mi][ni], 0, 0, 0);
  __builtin_amdgcn_s_setprio(0);
  asm volatile("" ::: "memory");
  __builtin_amdgcn_s_barrier();
  // ---------------- P2: reads a1 | stage B-k1(T+1) ----------------
  bf16x8 a1[4];
#pragma unroll
  for (int mi = 0; mi < 4; mi++)
    a1[mi] = *reinterpret_cast<const bf16x8*>(smem + aoffA + rb + 4096 + mi * 1024);
  if (T + 1 < NT) stage_half(smem, bs.B0, bs.B1, tQ, 32768, 1, T + 1);
  asm volatile("" ::: "memory");
  __builtin_amdgcn_s_barrier();
  __builtin_amdgcn_s_setprio(1);
#pragma unroll
  for (int mi = 0; mi < 4; mi++)
#pragma unroll
    for (int ni = 0; ni < 4; ni++)
      acc[4 + mi][ni] = __builtin_amdgcn_mfma_f32_16x16x32_bf16(a1[mi], b0[ni], acc[4 + mi][ni], 0, 0, 0);
  __builtin_amdgcn_s_setprio(0);
  asm volatile("" ::: "memory");
  __builtin_amdgcn_s_barrier();
  // ---------------- P3: reads a2,b1 | stage A-k0(T+2) ----------------
  bf16x8 a2[4], b1[4];
#pragma unroll
  for (int mi = 0; mi < 4; mi++)
    a2[mi] = *reinterpret_cast<const bf16x8*>(smem + aoffA + rb + 16384 + mi * 1024);
#pragma unroll
  for (int ni = 0; ni < 4; ni++)
    b1[ni] = *reinterpret_cast<const bf16x8*>(smem + aoffB + rb + 49152 + ni * 1024);
  if (T + 2 < NT) stage_half(smem, bs.A0, bs.A1, tQ, 0, 0, T + 2);
  asm volatile("" ::: "memory");
  __builtin_amdgcn_s_barrier();
  __builtin_amdgcn_s_setprio(1);
#pragma unroll
  for (int mi = 0; mi < 4; mi++)
#pragma unroll
    for (int ni = 0; ni < 4; ni++)
      acc[mi][ni] = __builtin_amdgcn_mfma_f32_16x16x32_bf16(a2[mi], b1[ni], acc[mi][ni], 0, 0, 0);
  __builtin_amdgcn_s_setprio(0);
  asm volatile("" ::: "memory");
  __builtin_amdgcn_s_barrier();
  // ---------------- P4: reads a3 | stage B-k0(T+2) ----------------
  bf16x8 a3[4];
#pragma unroll
  for (int mi = 0; mi < 4; mi++)
    a3[mi] = *reinterpret_cast<const bf16x8*>(smem + aoffA + rb + 20480 + mi * 1024);
  if (T + 2 < NT) stage_half(smem, bs.B0, bs.B1, tQ, 32768, 0, T + 2);
  asm volatile("" ::: "memory");
  __builtin_amdgcn_s_barrier();
  __builtin_amdgcn_s_setprio(1);
#pragma unroll
  for (int mi = 0; mi < 4; mi++)
#pragma unroll
    for (int ni = 0; ni < 4; ni++)
      acc[4 + mi][ni] = __builtin_amdgcn_mfma_f32_16x16x32_bf16(a3[mi], b1[ni], acc[4 + mi][ni], 0, 0, 0);
  __builtin_amdgcn_s_setprio(0);
  if (T < NT - 1) {
    if (T < NT - 2) asm volatile("s_waitcnt vmcnt(4)" ::: "memory");
    else            asm volatile("s_waitcnt vmcnt(0)" ::: "memory");
    __builtin_amdgcn_s_barrier();
  }
}

// ---------------------------------------------------------------- 256x256 8-phase GEMM (NT)
// r4 grid/ledger (one (bm,bn) tile per block, XCD-chunked swizzle) with
// precomputed per-lane global bases + swizzled LDS read offsets.
template <int MODE>
__global__ __launch_bounds__(512, 1)
void gemm256_kernel(const __bf16* __restrict__ A, const __bf16* __restrict__ Bw,
                    const float* __restrict__ bias0, const float* __restrict__ bias1,
                    const float* __restrict__ bias2,
                    __bf16* __restrict__ outq, __bf16* __restrict__ outkT,
                    __bf16* __restrict__ outvT, float* __restrict__ outf) {
  extern __shared__ char smem[];
  constexpr int NT = 16;                     // K/64
  constexpr int NBN = (MODE == 0) ? 12 : 4;  // N/256
  constexpr int NWG = 128 * NBN;
  constexpr int CPX = NWG / 8;

  const int raw = blockIdx.x;
  const int wgid = (raw & 7) * CPX + (raw >> 3);   // XCD-chunked swizzle (T1)
  const int bm = wgid / NBN;
  const int bn = wgid - bm * NBN;
  const int m0 = bm * 256, j0 = bn * 256;

  const int tid = threadIdx.x;
  const int l = tid & 63;
  const int w = tid >> 6;
  const int wm = w >> 2, wn = w & 3;
  const int lrow = l & 15, g16 = l >> 4;
  const int arow = wm * 128 + lrow;
  const int brow = wn * 64 + lrow;

  // per-lane swizzled LDS read bases (XOR bits invariant under +16/+64 rows)
  const int aoffA = (arow * 64 + g16 * 16) ^ (((arow >> 1) & 3) << 4);
  const int aoffB = (brow * 64 + g16 * 16) ^ (((brow >> 1) & 3) << 4);

  // per-lane staging geometry
  const int tQ = tid * 16;
  int rowQ[2], colQ[2];
#pragma unroll
  for (int i = 0; i < 2; i++) {
    const int Q = i * 8192 + tQ;
    const int Ls = Q ^ (((Q >> 7) & 3) << 4);
    rowQ[i] = Ls >> 6; colQ[i] = (Ls & 63) >> 1;
  }
  Bases bs;
  bs.A0 = A  + (size_t)(m0 + rowQ[0]) * 1024 + colQ[0];
  bs.A1 = A  + (size_t)(m0 + rowQ[1]) * 1024 + colQ[1];
  bs.B0 = Bw + (size_t)(j0 + rowQ[0]) * 1024 + colQ[0];
  bs.B1 = Bw + (size_t)(j0 + rowQ[1]) * 1024 + colQ[1];

  f32x4 acc[8][4] = {};

  // ---- prologue: k0(0),k1(0),k0(1); force tile0 (8), keep 4 in flight
  stage_half(smem, bs.A0, bs.A1, tQ, 0, 0, 0);
  stage_half(smem, bs.B0, bs.B1, tQ, 32768, 0, 0);
  stage_half(smem, bs.A0, bs.A1, tQ, 0, 1, 0);
  stage_half(smem, bs.B0, bs.B1, tQ, 32768, 1, 0);
  stage_half(smem, bs.A0, bs.A1, tQ, 0, 0, 1);
  stage_half(smem, bs.B0, bs.B1, tQ, 32768, 0, 1);
  asm volatile("s_waitcnt vmcnt(4)" ::: "memory");
  __builtin_amdgcn_s_barrier();

  for (int T = 0; T < NT; T += 2) {
    do_tile(smem, acc, bs, tQ, aoffA, aoffB, T, 0, NT);
    do_tile(smem, acc, bs, tQ, aoffA, aoffB, T + 1, 1, NT);
  }

  // ------------- epilogue (C frag: col = l&15, row = g16*4 + r) -------------
  const int jl0 = wn * 64 + lrow;
  if constexpr (MODE == 0) {
    const int sel = j0 >> 10;          // 0=q, 1=k, 2=v
    const int jb = j0 & 1023;
    const int jl = jb + jl0;
    const float* bias = (sel == 0) ? bias0 : ((sel == 1) ? bias1 : bias2);
    float bj[4];
#pragma unroll
    for (int ni = 0; ni < 4; ni++) bj[ni] = bias[jl + ni * 16];
    if (sel == 0) {
      __bf16* qb = outq + (size_t)(m0 + wm * 128 + g16 * 4) * 1024 + jl;
      const int mrel = (m0 & (NSEQ - 1)) + wm * 128 + g16 * 4;
#pragma unroll
      for (int mi = 0; mi < 8; mi++)
#pragma unroll
        for (int r = 0; r < 4; r++) {
          const float dec = __expf(-(float)(mrel + mi * 16 + r) * (1.0f / NSEQ));
#pragma unroll
          for (int ni = 0; ni < 4; ni++)
            qb[mi * 16384 + r * 1024 + ni * 16] =
                (__bf16)(fmaxf(acc[mi][ni][r] + bj[ni], 0.f) * dec);
        }
    } else {
      const int bidx = m0 >> 9;
      const int n0b = (m0 & (NSEQ - 1)) + wm * 128 + g16 * 4;
      __bf16* dst = (sel == 1) ? outkT : outvT;
      __bf16* cp[4];
#pragma unroll
      for (int ni = 0; ni < 4; ni++) {
        const int j = jl + ni * 16;
        cp[ni] = dst + (size_t)((bidx * NHEAD + (j >> 6)) * DHEAD + (j & 63)) * NSEQ + n0b;
      }
#pragma unroll
      for (int mi = 0; mi < 8; mi++) {
        float dec4[4];
        if (sel == 1) {
#pragma unroll
          for (int r = 0; r < 4; r++)
            dec4[r] = __expf(-(float)(n0b + mi * 16 + r) * (1.0f / NSEQ));
        }
#pragma unroll
        for (int ni = 0; ni < 4; ni++) {
          bf16x4 pk;
#pragma unroll
          for (int r = 0; r < 4; r++) {
            float val = acc[mi][ni][r] + bj[ni];
            if (sel == 1) val = fmaxf(val, 0.f) * dec4[r];
            pk[r] = (__bf16)val;
          }
          *reinterpret_cast<bf16x4*>(cp[ni] + mi * 16) = pk;
        }
      }
    }
  } else {
    const int jl = j0 + jl0;
    float bj[4];
#pragma unroll
    for (int ni = 0; ni < 4; ni++) bj[ni] = bias0[jl + ni * 16];
    float* fb = outf + (size_t)(m0 + wm * 128 + g16 * 4) * 1024 + jl;
#pragma unroll
    for (int mi = 0; mi < 8; mi++)
#pragma unroll
      for (int ni = 0; ni < 4; ni++)
#pragma unroll
        for (int r = 0; r < 4; r++)
          fb[mi * 16384 + r * 1024 + ni * 16] = acc[mi][ni][r] + bj[ni];
  }
}

// ---------------------------------------------------------------- attention core
// one block per (b,h); 256 threads = 4 waves; single barrier.
// KV phase also accumulates Ksum (shfl-reduced from the K fragments);
// PV phase computes denom in-register from the q fragments + register Ksum.
__global__ void attn_kernel(const __bf16* __restrict__ qf, const __bf16* __restrict__ kfT,
                            const __bf16* __restrict__ vT, __bf16* __restrict__ attn) {
  const int bh = blockIdx.x;                 // b*16 + h
  const int b = bh >> 4, h = bh & 15;
  const __bf16* kT = kfT + (size_t)bh * DHEAD * NSEQ;
  const __bf16* vTp = vT + (size_t)bh * DHEAD * NSEQ;
  const __bf16* qp = qf + (size_t)b * NSEQ * DMODEL + h * DHEAD;
  __bf16* op = attn + (size_t)b * NSEQ * DMODEL + h * DHEAD;

  const int tid = threadIdx.x;
  const int l = tid & 63;
  const int w = tid >> 6;
  const int lrow = l & 15, g16 = l >> 4, lk = g16 * 8;

  __shared__ __bf16 KVT[64][88];      // KVT[e][d] = KV[d][e]
  __shared__ float ksum_s[64];

  // ---- KV[d,e] = sum_n kfT[d,n]*vT[e,n] + Ksum[d]; wave w owns d in [w*16,+16)
  {
    f32x4 kv[4] = {};
    float sk = 0.f;
    const int arow = w * 16 + lrow;
    for (int kk = 0; kk < NSEQ; kk += 32) {
      bf16x8 a = *reinterpret_cast<const bf16x8*>(&kT[(size_t)arow * NSEQ + kk + lk]);
#pragma unroll
      for (int j = 0; j < 8; j++) sk += (float)a[j];
#pragma unroll
      for (int ni = 0; ni < 4; ni++) {
        bf16x8 bv = *reinterpret_cast<const bf16x8*>(&vTp[(size_t)(ni * 16 + lrow) * NSEQ + kk + lk]);
        kv[ni] = __builtin_amdgcn_mfma_f32_16x16x32_bf16(a, bv, kv[ni], 0, 0, 0);
      }
    }
    // Ksum[arow]: reduce sk over the 4 lanes sharing arow (lane^16, lane^32)
    sk += __shfl_xor(sk, 16);
    sk += __shfl_xor(sk, 32);
    ksum_s[arow] = sk;                 // 4 lanes write identical value
    const int d0 = w * 16 + g16 * 4;
#pragma unroll
    for (int ni = 0; ni < 4; ni++) {
      const int e = ni * 16 + lrow;
      bf16x4 pk;
#pragma unroll
      for (int r = 0; r < 4; r++) pk[r] = (__bf16)kv[ni][r];
      *reinterpret_cast<bf16x4*>(&KVT[e][d0]) = pk;
    }
  }
  __syncthreads();

  // Ksum slices into registers (columns this lane's q-fragments cover)
  float Ks0[8], Ks1[8];
#pragma unroll
  for (int j = 0; j < 8; j++) { Ks0[j] = ksum_s[lk + j]; Ks1[j] = ksum_s[32 + lk + j]; }

  // ---- out[n,e] = (sum_d qf[n,d]*KVT[e,d]) / (qf[n,:].Ksum + eps)
  for (int t = 0; t < 8; t++) {
    const int nrow = t * 64 + w * 16 + lrow;
    bf16x8 a0 = *reinterpret_cast<const bf16x8*>(&qp[(size_t)nrow * DMODEL + lk]);
    bf16x8 a1 = *reinterpret_cast<const bf16x8*>(&qp[(size_t)nrow * DMODEL + 32 + lk]);
    // denom partial for row nrow
    float dp = 0.f;
#pragma unroll
    for (int j = 0; j < 8; j++) dp += (float)a0[j] * Ks0[j] + (float)a1[j] * Ks1[j];
    dp += __shfl_xor(dp, 16);
    dp += __shfl_xor(dp, 32);
    dp += 1e-6f;                        // every lane holds denom(nrow)
    f32x4 o[4] = {};
#pragma unroll
    for (int ni = 0; ni < 4; ni++) {
      bf16x8 b0 = *reinterpret_cast<const bf16x8*>(&KVT[ni * 16 + lrow][lk]);
      bf16x8 b1 = *reinterpret_cast<const bf16x8*>(&KVT[ni * 16 + lrow][32 + lk]);
      o[ni] = __builtin_amdgcn_mfma_f32_16x16x32_bf16(a0, b0, o[ni], 0, 0, 0);
      o[ni] = __builtin_amdgcn_mfma_f32_16x16x32_bf16(a1, b1, o[ni], 0, 0, 0);
    }
    // fetch denom for output rows g16*4+r (held by lane with lrow == g16*4+r)
    float den[4];
#pragma unroll
    for (int r = 0; r < 4; r++) den[r] = __shfl(dp, g16 * 4 + r);
    const int n0 = t * 64 + w * 16 + g16 * 4;
#pragma unroll
    for (int ni = 0; ni < 4; ni++) {
      const int e = ni * 16 + lrow;
#pragma unroll
      for (int r = 0; r < 4; r++)
        op[(size_t)(n0 + r) * DMODEL + e] = (__bf16)(o[ni][r] / den[r]);
    }
  }
}

// ---------------------------------------------------------------- launch
extern "C" void kernel_launch(void* const* d_in, const int* in_sizes, int n_in,
                              void* d_out, int out_size, void* d_ws, size_t ws_size,
                              hipStream_t stream) {
  (void)in_sizes; (void)n_in; (void)out_size; (void)ws_size;
  const float* x  = (const float*)d_in[0];
  const float* Wq = (const float*)d_in[1];
  const float* bq = (const float*)d_in[2];
  const float* Wk = (const float*)d_in[3];
  const float* bk = (const float*)d_in[4];
  const float* Wv = (const float*)d_in[5];
  const float* bv = (const float*)d_in[6];
  const float* Wo = (const float*)d_in[7];
  const float* bo = (const float*)d_in[8];
  float* out = (float*)d_out;

  char* ws = (char*)d_ws;
  __bf16* xb    = (__bf16*)(ws);                    // 64 MB  (reused as attn output)
  __bf16* qf    = (__bf16*)(ws + 67108864);         // 64 MB
  __bf16* kfT   = (__bf16*)(ws + 134217728);        // 64 MB
  __bf16* vT    = (__bf16*)(ws + 201326592);        // 64 MB
  __bf16* Wqkvb = (__bf16*)(ws + 268435456);        // 6 MB
  __bf16* Wob   = (__bf16*)(ws + 274726912);        // 2 MB
  __bf16* attnb = xb;                               // alias: xb dead after QKV GEMM

  cvt_all_kernel<<<4096, 256, 0, stream>>>(x, Wq, Wk, Wv, Wo, xb, Wqkvb, Wob);

  gemm256_kernel<0><<<1536, 512, 131072, stream>>>(xb, Wqkvb, bq, bk, bv,
                                                   qf, kfT, vT, nullptr);
  attn_kernel<<<NBATCH * NHEAD, 256, 0, stream>>>(qf, kfT, vT, attnb);
  gemm256_kernel<1><<<512, 512, 131072, stream>>>(attnb, Wob, bo, nullptr, nullptr,
                                                  nullptr, nullptr, nullptr, out);
}